// Round 3
// baseline (164.824 us; speedup 1.0000x reference)
//
#include <hip/hip_runtime.h>

// Reference constants
#define NUM_EMB    8192
#define EMB_DIM    512
#define BATCH_N    16384
#define BD         (BATCH_N * EMB_DIM)   // 8388608 elems in quantized (and diff)
#define TOTAL_OUT  (2 * BD + 1)          // 16777217 fp32 elems in d_out
#define NCHUNK     (TOTAL_OUT / 4)       // 4194304 full float4 chunks (+1 tail)
#define QCHUNK_END (BD / 4)              // 2097152: boundary chunk index
#define NBLOCKS    2048
#define NTHREADS   256
#define NTOTAL     (NBLOCKS * NTHREADS)  // 524288 threads = full residency

// Self-cleaning cross-block scratch: module-load init once; the last block of
// every execution resets both to 0 after use, so graph replays start clean.
__device__ float g_acc  = 0.0f;
__device__ int   g_done = 0;

__global__ __launch_bounds__(NTHREADS, 4) void vq_fused(
        const int* __restrict__ x, const float* __restrict__ W,
        float* __restrict__ out) {
    const int tid = blockIdx.x * NTHREADS + threadIdx.x;
    float4* out4 = (float4*)out;

    // ---- Phase 1a: issue sum-of-squares loads (1048576 float4s, 2/thread) ----
    const float4* W4 = (const float4*)W;
    float4 a = W4[tid];
    float4 b = W4[tid + NTOTAL];

    // ---- Phase 3 first: diff region = zeros, chunks (QCHUNK_END, NCHUNK) ----
    // Pure fill-style stores, no dependencies — overlaps the phase-1 loads.
#pragma unroll
    for (int k = 0; k < 4; ++k) {
        int c = QCHUNK_END + 1 + tid + k * NTOTAL;
        if (c < NCHUNK) out4[c] = make_float4(0.f, 0.f, 0.f, 0.f);
    }
    if (tid == 0) {
        // boundary chunk: [last quantized elem, diff0, diff1, diff2]
        float w = W[x[BATCH_N - 1] * EMB_DIM + 511];
        out4[QCHUNK_END] = make_float4(w, 0.f, 0.f, 0.f);
    } else if (tid == 1) {
        out[TOTAL_OUT - 1] = 0.0f;   // final odd diff element
    }

    // ---- Phase 1b: reduce W^2, block atomicAdd, done-counter ----
    float s = a.x*a.x + a.y*a.y + a.z*a.z + a.w*a.w
            + b.x*b.x + b.y*b.y + b.z*b.z + b.w*b.w;
#pragma unroll
    for (int off = 32; off > 0; off >>= 1) s += __shfl_down(s, off, 64);
    __shared__ float ls[NTHREADS / 64];
    if ((threadIdx.x & 63) == 0) ls[threadIdx.x >> 6] = s;
    __syncthreads();
    if (threadIdx.x == 0) {
        float bs = ls[0] + ls[1] + ls[2] + ls[3];
        atomicAdd(&g_acc, bs);
        __threadfence();                       // publish before signaling done
        int prev = atomicAdd(&g_done, 1);
        if (prev == NBLOCKS - 1) {
            // all 2048 partials are in: finalize loss + chunk 0
            __threadfence();
            float total = atomicAdd(&g_acc, 0.0f);   // device-coherent read
            float loss = 0.25f * total;              // diff-term is exactly 0
            int k = x[0];
            float4 v = *(const float4*)(W + k * EMB_DIM);
            out4[0] = make_float4(loss, v.x, v.y, v.z);
            // reset for the next graph-replayed execution
            atomicExch(&g_acc, 0.0f);
            atomicExch(&g_done, 0);
        }
    }

    // ---- Phase 2: quantized = W[x], chunks [1, QCHUNK_END) ----
    // Chunk c covers out elems 4c..4c+3 -> quantized idx 4c-1..4c+2.
    // Row of idx 4c is b1=c>>7; the misphased first elem is row b1 except
    // when j1==0 (then previous row). W is L2/L3-hot after phase 1.
#pragma unroll
    for (int k = 0; k < 4; ++k) {
        int c = 1 + tid + k * NTOTAL;
        if (c < QCHUNK_END) {
            int j1 = (c << 2) & 511;
            int b1 = c >> 7;
            int k1 = x[b1];
            int k0 = (j1 == 0) ? x[b1 - 1] : k1;
            int j0 = (j1 - 1) & 511;
            float  w0 = W[k0 * EMB_DIM + j0];
            float4 v  = *(const float4*)(W + k1 * EMB_DIM + j1);
            out4[c] = make_float4(w0, v.x, v.y, v.z);
        }
    }
}

extern "C" void kernel_launch(void* const* d_in, const int* in_sizes, int n_in,
                              void* d_out, int out_size, void* d_ws, size_t ws_size,
                              hipStream_t stream) {
    const int*   x = (const int*)d_in[0];    // int32 indices, 16384
    const float* W = (const float*)d_in[1];  // fp32 codebook, 8192x512
    float* out     = (float*)d_out;          // fp32: [loss | quantized | diff]

    vq_fused<<<NBLOCKS, NTHREADS, 0, stream>>>(x, W, out);
}

// Round 4
// 96.360 us; speedup vs baseline: 1.7105x; 1.7105x over previous
//
#include <hip/hip_runtime.h>

// Reference constants
#define NUM_EMB    8192
#define EMB_DIM    512
#define BATCH_N    16384
#define BD         (BATCH_N * EMB_DIM)   // 8388608 elems in quantized (and diff)
#define TOTAL_OUT  (2 * BD + 1)          // 16777217 fp32 elems in d_out
#define NCHUNK     (TOTAL_OUT / 4)       // 4194304 full float4 chunks (+1 tail)
#define QCHUNK_END (BD / 4)              // 2097152: boundary chunk index
#define NBLOCKS    2048
#define NTHREADS   256
#define NTOTAL     (NBLOCKS * NTHREADS)  // 524288 threads

// K1 -> K2 handoff. Every K1 block unconditionally writes its slot each call,
// so no zeroing is needed; kernel-boundary ordering makes it visible to K2
// (R2 validated this path with absmax 0).
__device__ float g_partial[NBLOCKS];

// ---- K1: per-block partial sums of W^2 (16 MB fp32 stream) ----
__global__ __launch_bounds__(NTHREADS) void vq_sum(const float* __restrict__ W) {
    int tid = blockIdx.x * NTHREADS + threadIdx.x;
    const float4* W4 = (const float4*)W;            // 1048576 float4s, 2/thread
    float4 a = W4[tid];
    float4 b = W4[tid + NTOTAL];
    float s = a.x*a.x + a.y*a.y + a.z*a.z + a.w*a.w
            + b.x*b.x + b.y*b.y + b.z*b.z + b.w*b.w;
#pragma unroll
    for (int off = 32; off > 0; off >>= 1) s += __shfl_down(s, off, 64);
    __shared__ float ls[NTHREADS / 64];
    if ((threadIdx.x & 63) == 0) ls[threadIdx.x >> 6] = s;
    __syncthreads();
    if (threadIdx.x == 0) g_partial[blockIdx.x] = ls[0] + ls[1] + ls[2] + ls[3];
}

// ---- K2: out = [loss | quantized=W[x] | diff=0], aligned float4 chunks ----
// Chunk c covers out elems 4c..4c+3 (quantized idx = elem-1). Each thread owns
// exactly 4 diff chunks + 4 quantized chunks, grid-strided for coalescing.
// No atomics, no fences, no cross-block communication except g_partial reads.
__global__ __launch_bounds__(NTHREADS) void vq_write(const int* __restrict__ x,
        const float* __restrict__ W, float* __restrict__ out) {
    const int tid = blockIdx.x * NTHREADS + threadIdx.x;
    float4* out4 = (float4*)out;

    // Diff region: chunks (QCHUNK_END, NCHUNK) = 2097151 chunks of zeros.
    // Pure independent stores — issue first, fill-style.
#pragma unroll
    for (int k = 0; k < 4; ++k) {
        int c = QCHUNK_END + 1 + tid + k * NTOTAL;
        if (c < NCHUNK) out4[c] = make_float4(0.f, 0.f, 0.f, 0.f);
    }
    if (tid == 0) out[TOTAL_OUT - 1] = 0.0f;   // final odd diff element

    // Quantized region: chunks [1, QCHUNK_END] = 2097152 = exactly 4/thread.
#pragma unroll
    for (int k = 0; k < 4; ++k) {
        int c = 1 + tid + k * NTOTAL;
        if (c == QCHUNK_END) {
            // boundary: [quantized last elem (b=BATCH-1, j=511), diff zeros]
            float w = W[x[BATCH_N - 1] * EMB_DIM + 511];
            out4[c] = make_float4(w, 0.f, 0.f, 0.f);
        } else {
            int j1 = (c << 2) & 511;             // aligned in-row offset (mult of 4)
            int b1 = c >> 7;                     // batch row for idx 4c
            int k1 = x[b1];
            int k0 = (j1 == 0) ? x[b1 - 1] : k1; // misphased elem's row
            int j0 = (j1 - 1) & 511;
            float  w0 = W[k0 * EMB_DIM + j0];
            float4 v  = *(const float4*)(W + k1 * EMB_DIM + j1);
            out4[c] = make_float4(w0, v.x, v.y, v.z);
        }
    }

    // Block 0: reduce 2048 partials -> loss, write chunk 0 (only writer of it).
    if (blockIdx.x == 0) {
        __shared__ float red[NTHREADS];
        float s = 0.0f;
        for (int i = threadIdx.x; i < NBLOCKS; i += NTHREADS) s += g_partial[i];
        red[threadIdx.x] = s;
        __syncthreads();
        for (int st = NTHREADS / 2; st > 0; st >>= 1) {
            if (threadIdx.x < st) red[threadIdx.x] += red[threadIdx.x + st];
            __syncthreads();
        }
        if (threadIdx.x == 0) {
            float loss = 0.25f * red[0];         // diff-term is exactly 0
            int k = x[0];
            float4 v = *(const float4*)(W + k * EMB_DIM);
            out4[0] = make_float4(loss, v.x, v.y, v.z);
        }
    }
}

extern "C" void kernel_launch(void* const* d_in, const int* in_sizes, int n_in,
                              void* d_out, int out_size, void* d_ws, size_t ws_size,
                              hipStream_t stream) {
    const int*   x = (const int*)d_in[0];    // int32 indices, 16384
    const float* W = (const float*)d_in[1];  // fp32 codebook, 8192x512
    float* out     = (float*)d_out;          // fp32: [loss | quantized | diff]

    vq_sum<<<NBLOCKS, NTHREADS, 0, stream>>>(W);
    vq_write<<<NBLOCKS, NTHREADS, 0, stream>>>(x, W, out);
}

// Round 5
// 94.648 us; speedup vs baseline: 1.7414x; 1.0181x over previous
//
#include <hip/hip_runtime.h>

// Reference constants
#define NUM_EMB    8192
#define EMB_DIM    512
#define BATCH_N    16384
#define BD         (BATCH_N * EMB_DIM)   // 8388608 elems in quantized (and diff)
#define TOTAL_OUT  (2 * BD + 1)          // 16777217 fp32 elems in d_out
#define NCHUNK     (TOTAL_OUT / 4)       // 4194304 full float4 chunks (+1 tail)
#define QCHUNK_END (BD / 4)              // 2097152: boundary chunk index
#define NBLOCKS    2048
#define NTHREADS   256
#define NTOTAL     (NBLOCKS * NTHREADS)  // 524288 threads = 8192 waves

__device__ float g_partial[NBLOCKS];     // K1->K2 handoff (validated R2/R4)

// ---- K1: per-block partial sums of W^2 (16 MB fp32 stream, ~3 us) ----
__global__ __launch_bounds__(NTHREADS) void vq_sum(const float* __restrict__ W) {
    int tid = blockIdx.x * NTHREADS + threadIdx.x;
    const float4* W4 = (const float4*)W;
    float4 a = W4[tid];
    float4 b = W4[tid + NTOTAL];
    float s = a.x*a.x + a.y*a.y + a.z*a.z + a.w*a.w
            + b.x*b.x + b.y*b.y + b.z*b.z + b.w*b.w;
#pragma unroll
    for (int off = 32; off > 0; off >>= 1) s += __shfl_down(s, off, 64);
    __shared__ float ls[NTHREADS / 64];
    if ((threadIdx.x & 63) == 0) ls[threadIdx.x >> 6] = s;
    __syncthreads();
    if (threadIdx.x == 0) g_partial[blockIdx.x] = ls[0] + ls[1] + ls[2] + ls[3];
}

// ---- K2: row-streaming writer ----
// Wave w owns batch rows b = 2w, 2w+1. For row b it writes chunks
// 128b..128b+127 (chunk 128b+i = [row-b elem 4i-1 .. 4i+2]; i=0 borrows the
// previous row's elem 511). The +1 phase shift is done with __shfl_up, so per
// row each lane does: 2 aligned float4 loads -> 1 shuffle -> 2 aligned stores.
__global__ __launch_bounds__(NTHREADS) void vq_write(const int* __restrict__ x,
        const float* __restrict__ W, float* __restrict__ out) {
    const int tid  = blockIdx.x * NTHREADS + threadIdx.x;
    const int lane = threadIdx.x & 63;
    const int wave = (tid >> 6);               // 0..8191
    float4* out4 = (float4*)out;

    const int b0 = 2 * wave;
    const int b1 = 2 * wave + 1;

    // Issue the row-index loads first (broadcast; L2-hot after first waves).
    int k0 = x[b0];
    int k1 = x[b1];
    int kp = (b0 > 0) ? x[b0 - 1] : 0;         // row before b0 (unused for b0==0)

    // Diff region: 2097151 zero chunks, fire-and-forget stores that overlap
    // the index/row load latency.
#pragma unroll
    for (int k = 0; k < 4; ++k) {
        int c = QCHUNK_END + 1 + tid + k * NTOTAL;
        if (c < NCHUNK) out4[c] = make_float4(0.f, 0.f, 0.f, 0.f);
    }
    if (blockIdx.x == 1 && threadIdx.x == 0) {
        out[TOTAL_OUT - 1] = 0.0f;                       // odd tail diff elem
        float w = W[x[BATCH_N - 1] * EMB_DIM + 511];     // boundary chunk
        out4[QCHUNK_END] = make_float4(w, 0.f, 0.f, 0.f);
    }

    // Row data: both rows' loads issued back-to-back (independent, stay in flight).
    const float4* R0 = (const float4*)(W + k0 * EMB_DIM);
    const float4* R1 = (const float4*)(W + k1 * EMB_DIM);
    float4 a0 = R0[2 * lane], a1 = R0[2 * lane + 1];
    float4 c0 = R1[2 * lane], c1 = R1[2 * lane + 1];
    float p0 = W[kp * EMB_DIM + 511];          // prev-row elem 511 (broadcast)
    float p1 = W[k0 * EMB_DIM + 511];          // row b0 elem 511 (L1-hot)

    // Row b0: lane l covers row elems 8l..8l+7 -> chunks 128*b0 + 2l, +2l+1.
    {
        float pw = __shfl_up(a1.w, 1, 64);     // lane l-1's elem 8l-1
        float first = (lane == 0) ? p0 : pw;
        int cb = 128 * b0;
        if (b0 != 0 || lane != 0)              // chunk 0 is the loss chunk
            out4[cb + 2 * lane]     = make_float4(first, a0.x, a0.y, a0.z);
        out4[cb + 2 * lane + 1]     = make_float4(a0.w,  a1.x, a1.y, a1.z);
    }
    // Row b1
    {
        float pw = __shfl_up(c1.w, 1, 64);
        float first = (lane == 0) ? p1 : pw;
        int cb = 128 * b1;
        out4[cb + 2 * lane]         = make_float4(first, c0.x, c0.y, c0.z);
        out4[cb + 2 * lane + 1]     = make_float4(c0.w,  c1.x, c1.y, c1.z);
    }

    // Block 0: reduce partials -> loss, sole writer of chunk 0.
    if (blockIdx.x == 0) {
        __shared__ float red[NTHREADS];
        float s = 0.0f;
        for (int i = threadIdx.x; i < NBLOCKS; i += NTHREADS) s += g_partial[i];
        red[threadIdx.x] = s;
        __syncthreads();
        for (int st = NTHREADS / 2; st > 0; st >>= 1) {
            if (threadIdx.x < st) red[threadIdx.x] += red[threadIdx.x + st];
            __syncthreads();
        }
        if (threadIdx.x == 0) {
            float loss = 0.25f * red[0];       // diff loss term is exactly 0
            int k = x[0];
            float4 v = *(const float4*)(W + k * EMB_DIM);
            out4[0] = make_float4(loss, v.x, v.y, v.z);
        }
    }
}

extern "C" void kernel_launch(void* const* d_in, const int* in_sizes, int n_in,
                              void* d_out, int out_size, void* d_ws, size_t ws_size,
                              hipStream_t stream) {
    const int*   x = (const int*)d_in[0];    // int32 indices, 16384
    const float* W = (const float*)d_in[1];  // fp32 codebook, 8192x512
    float* out     = (float*)d_out;          // fp32: [loss | quantized | diff]

    vq_sum<<<NBLOCKS, NTHREADS, 0, stream>>>(W);
    vq_write<<<NBLOCKS, NTHREADS, 0, stream>>>(x, W, out);
}